// Round 1
// baseline (1685.908 us; speedup 1.0000x reference)
//
#include <hip/hip_runtime.h>
#include <hip/hip_bf16.h>
#include <math.h>

#define QDIM 64
#define KDIM 2
#define NDIM 32
#define MDIM 64
#define EDIM 256
#define DDIM 1024
#define RDIM 200
#define SDIM 8192
#define GCOUNT (QDIM * KDIM * NDIM)  // 4096 groups

__device__ __forceinline__ float fast_tanh(float x) {
    x = fminf(fmaxf(x, -15.0f), 15.0f);
    float e = __expf(2.0f * x);
    return (e - 1.0f) / (e + 1.0f);
}

// K0: copy hidden_states -> out (out = hs, rows later incremented by K5)
__global__ __launch_bounds__(256) void copy_kernel(const float4* __restrict__ src,
                                                   float4* __restrict__ dst, int n4) {
    int i = blockIdx.x * 256 + threadIdx.x;
    int stride = gridDim.x * 256;
    for (; i < n4; i += stride) dst[i] = src[i];
}

// K1: gq[q][d] = tanh(hs[gnn_idx[q]] @ Wq + bq)
__global__ __launch_bounds__(256) void gq_kernel(const float* __restrict__ hs,
                                                 const int* __restrict__ gnn_idx,
                                                 const float* __restrict__ Wq,
                                                 const float* __restrict__ bq,
                                                 float* __restrict__ gqo) {
    int q = blockIdx.x, t = threadIdx.x;
    __shared__ float row[DDIM];
    const float* src = hs + (size_t)gnn_idx[q] * DDIM;
    for (int i = t; i < DDIM; i += 256) row[i] = src[i];
    __syncthreads();
    float a0 = bq[t], a1 = bq[t + 256], a2 = bq[t + 512], a3 = bq[t + 768];
    for (int k = 0; k < DDIM; ++k) {
        float r = row[k];
        const float* wr = Wq + (size_t)k * DDIM;
        a0 += r * wr[t];
        a1 += r * wr[t + 256];
        a2 += r * wr[t + 512];
        a3 += r * wr[t + 768];
    }
    float* o = gqo + q * DDIM;
    o[t] = fast_tanh(a0);
    o[t + 256] = fast_tanh(a1);
    o[t + 512] = fast_tanh(a2);
    o[t + 768] = fast_tanh(a3);
}

// K2: rel_prob[q][r] = softmax_r(hs[rel_idx[q]] @ Wc + bc)
__global__ __launch_bounds__(256) void relprob_kernel(const float* __restrict__ hs,
                                                      const int* __restrict__ rel_idx,
                                                      const float* __restrict__ Wc,
                                                      const float* __restrict__ bc,
                                                      float* __restrict__ rel_prob) {
    int q = blockIdx.x, t = threadIdx.x;
    __shared__ float row[DDIM];
    __shared__ float arr[256];
    const float* src = hs + (size_t)rel_idx[q] * DDIM;
    for (int i = t; i < DDIM; i += 256) row[i] = src[i];
    __syncthreads();
    float lg = -INFINITY;
    if (t < RDIM) {
        float a = bc[t];
        for (int k = 0; k < DDIM; ++k) a += row[k] * Wc[(size_t)k * RDIM + t];
        lg = a;
    }
    arr[t] = lg;
    __syncthreads();
    for (int s = 128; s > 0; s >>= 1) {
        if (t < s) arr[t] = fmaxf(arr[t], arr[t + s]);
        __syncthreads();
    }
    float mx = arr[0];
    __syncthreads();
    float ex = (t < RDIM) ? __expf(lg - mx) : 0.0f;
    arr[t] = ex;
    __syncthreads();
    for (int s = 128; s > 0; s >>= 1) {
        if (t < s) arr[t] += arr[t + s];
        __syncthreads();
    }
    float sm = arr[0];
    if (t < RDIM) rel_prob[q * RDIM + t] = ex / sm;
}

// K3: per-(q,k,n) group. Computes dots -> within-group softmax -> logits ->
// group-local exp-weights; emits gmax_n, den_n (unmasked), vec_n[e] (masked).
__global__ __launch_bounds__(256) void phase1_kernel(
    const float* __restrict__ nodes, const float* __restrict__ Wn,
    const float* __restrict__ bn, const float* __restrict__ gq,
    const float* __restrict__ rel_prob, const int* __restrict__ prob_idx,
    float* __restrict__ gvec, float* __restrict__ gden, float* __restrict__ gmx) {
    const int g = blockIdx.x;              // (q*K + k)*N + n
    const int q = g / (KDIM * NDIM);
    const int t = threadIdx.x;
    const int lane = t & 63;
    const int wid = t >> 6;

    __shared__ float lds_nodes[MDIM][EDIM];  // 64 KB group tile
    __shared__ float part[4][16];
    __shared__ float dots_s[MDIM];
    __shared__ float lvals[MDIM];

    // stage group tile (coalesced float4)
    {
        const float4* src = (const float4*)(nodes + (size_t)g * (MDIM * EDIM));
        float4* dst = (float4*)(&lds_nodes[0][0]);
#pragma unroll
        for (int i = 0; i < (MDIM * EDIM / 4) / 256; ++i) dst[t + i * 256] = src[t + i * 256];
    }
    const float4 bn4 = ((const float4*)bn)[t];               // d = 4t..4t+3
    const float4 gq4 = ((const float4*)(gq + (size_t)q * DDIM))[t];
    __syncthreads();

    const float4* Wn4 = (const float4*)Wn;
    // m-blocks of 16 rows; each thread owns d = 4t..4t+3
    for (int mb = 0; mb < 4; ++mb) {
        float acc[16][4];
#pragma unroll
        for (int mm = 0; mm < 16; ++mm) {
            acc[mm][0] = 0.f; acc[mm][1] = 0.f; acc[mm][2] = 0.f; acc[mm][3] = 0.f;
        }
        const float* nb = &lds_nodes[mb * 16][0];
        for (int e4 = 0; e4 < EDIM / 4; ++e4) {
            float4 w0 = Wn4[(size_t)(4 * e4 + 0) * (DDIM / 4) + t];
            float4 w1 = Wn4[(size_t)(4 * e4 + 1) * (DDIM / 4) + t];
            float4 w2 = Wn4[(size_t)(4 * e4 + 2) * (DDIM / 4) + t];
            float4 w3 = Wn4[(size_t)(4 * e4 + 3) * (DDIM / 4) + t];
#pragma unroll
            for (int mm = 0; mm < 16; ++mm) {
                const float4 nv = *(const float4*)(nb + mm * EDIM + 4 * e4);
                acc[mm][0] += nv.x * w0.x; acc[mm][0] += nv.y * w1.x;
                acc[mm][0] += nv.z * w2.x; acc[mm][0] += nv.w * w3.x;
                acc[mm][1] += nv.x * w0.y; acc[mm][1] += nv.y * w1.y;
                acc[mm][1] += nv.z * w2.y; acc[mm][1] += nv.w * w3.y;
                acc[mm][2] += nv.x * w0.z; acc[mm][2] += nv.y * w1.z;
                acc[mm][2] += nv.z * w2.z; acc[mm][2] += nv.w * w3.z;
                acc[mm][3] += nv.x * w0.w; acc[mm][3] += nv.y * w1.w;
                acc[mm][3] += nv.z * w2.w; acc[mm][3] += nv.w * w3.w;
            }
        }
        // tanh + dot with gq, reduce 256 threads -> dots[m]
#pragma unroll
        for (int mm = 0; mm < 16; ++mm) {
            float l = fast_tanh(acc[mm][0] + bn4.x) * gq4.x +
                      fast_tanh(acc[mm][1] + bn4.y) * gq4.y +
                      fast_tanh(acc[mm][2] + bn4.z) * gq4.z +
                      fast_tanh(acc[mm][3] + bn4.w) * gq4.w;
#pragma unroll
            for (int off = 32; off > 0; off >>= 1) l += __shfl_down(l, off);
            if (lane == 0) part[wid][mm] = l;
        }
        __syncthreads();
        if (t < 16) dots_s[mb * 16 + t] = part[0][t] + part[1][t] + part[2][t] + part[3][t];
        __syncthreads();
    }

    // wave 0: within-group softmax over m (dense, masked slots included),
    // logits = attn*prob*10, group max / exp / den
    if (t < 64) {
        float dv = dots_s[t];
        float mx = dv;
#pragma unroll
        for (int off = 32; off > 0; off >>= 1) mx = fmaxf(mx, __shfl_xor(mx, off));
        float ex = __expf(dv - mx);
        float sm = ex;
#pragma unroll
        for (int off = 32; off > 0; off >>= 1) sm += __shfl_xor(sm, off);
        float attn = ex / sm;
        float pr = rel_prob[(size_t)q * RDIM + prob_idx[g]];
        float lgv = attn * pr * 10.0f;
        float gm = lgv;
#pragma unroll
        for (int off = 32; off > 0; off >>= 1) gm = fmaxf(gm, __shfl_xor(gm, off));
        float el = __expf(lgv - gm);
        float den = el;
#pragma unroll
        for (int off = 32; off > 0; off >>= 1) den += __shfl_xor(den, off);
        float msk = (lds_nodes[t][0] != 0.0f) ? 1.0f : 0.0f;  // mask only the numerator
        lvals[t] = el * msk;
        if (t == 0) { gden[g] = den; gmx[g] = gm; }
    }
    __syncthreads();
    // vec_n[e] = sum_m nodes[m][e] * mask*exp(l - gmax_n); thread t <-> e
    float v = 0.f;
#pragma unroll 8
    for (int m = 0; m < MDIM; ++m) v += lds_nodes[m][t] * lvals[m];
    gvec[(size_t)g * EDIM + t] = v;
}

// K4: per-(q,k) combine 32 groups -> mean_emb[q,k,e]
__global__ __launch_bounds__(256) void combine_kernel(const float* __restrict__ gvec,
                                                      const float* __restrict__ gden,
                                                      const float* __restrict__ gmx,
                                                      float* __restrict__ memb) {
    int qk = blockIdx.x, t = threadIdx.x;
    __shared__ float sgm[NDIM], sden[NDIM];
    if (t < NDIM) {
        sgm[t] = gmx[qk * NDIM + t];
        sden[t] = gden[qk * NDIM + t];
    }
    __syncthreads();
    float gm = -INFINITY;
    for (int n = 0; n < NDIM; ++n) gm = fmaxf(gm, sgm[n]);
    float gs = 0.f;
    for (int n = 0; n < NDIM; ++n) gs += sden[n] * __expf(sgm[n] - gm);
    float me = 0.f;
    for (int n = 0; n < NDIM; ++n)
        me += gvec[(size_t)(qk * NDIM + n) * EDIM + t] * __expf(sgm[n] - gm);
    memb[(size_t)qk * EDIM + t] = me / (gs * (float)(NDIM * MDIM));
}

// K5: pooled = mean_k(mean_emb); out_row = tanh(pooled @ Wg + bg); d_out[gnn_idx[q]] += out_row
__global__ __launch_bounds__(256) void out_kernel(const float* __restrict__ memb,
                                                  const float* __restrict__ Wg,
                                                  const float* __restrict__ bg,
                                                  const int* __restrict__ gnn_idx,
                                                  float* __restrict__ out) {
    int q = blockIdx.x, t = threadIdx.x;
    __shared__ float pooled[EDIM];
    pooled[t] = 0.5f * (memb[(size_t)(q * 2 + 0) * EDIM + t] + memb[(size_t)(q * 2 + 1) * EDIM + t]);
    __syncthreads();
    float4 a = ((const float4*)bg)[t];  // d = 4t..4t+3
    const float4* Wg4 = (const float4*)Wg;
    for (int e = 0; e < EDIM; ++e) {
        float p = pooled[e];
        float4 w = Wg4[(size_t)e * (DDIM / 4) + t];
        a.x += p * w.x; a.y += p * w.y; a.z += p * w.z; a.w += p * w.w;
    }
    float4* op = (float4*)(out + (size_t)gnn_idx[q] * DDIM);
    float4 cur = op[t];
    cur.x += fast_tanh(a.x);
    cur.y += fast_tanh(a.y);
    cur.z += fast_tanh(a.z);
    cur.w += fast_tanh(a.w);
    op[t] = cur;
}

extern "C" void kernel_launch(void* const* d_in, const int* in_sizes, int n_in,
                              void* d_out, int out_size, void* d_ws, size_t ws_size,
                              hipStream_t stream) {
    const float* hs = (const float*)d_in[0];
    const float* nodes = (const float*)d_in[1];
    const int* prob_idx = (const int*)d_in[2];
    const int* gnn_idx = (const int*)d_in[3];
    const int* rel_idx = (const int*)d_in[4];
    const float* Wc = (const float*)d_in[5];
    const float* bc = (const float*)d_in[6];
    const float* Wq = (const float*)d_in[7];
    const float* bq = (const float*)d_in[8];
    const float* Wn = (const float*)d_in[9];
    const float* bn = (const float*)d_in[10];
    const float* Wg = (const float*)d_in[11];
    const float* bg = (const float*)d_in[12];
    float* out = (float*)d_out;
    float* ws = (float*)d_ws;

    // ws layout (floats): relprob[16384 pad] | gq[65536] | gvec[4096*256] | gden[4096] | gmax[4096] | memb[32768]
    float* relprob = ws;
    float* gqbuf = ws + 16384;
    float* gvec = gqbuf + (size_t)QDIM * DDIM;
    float* gdenA = gvec + (size_t)GCOUNT * EDIM;
    float* gmaxA = gdenA + GCOUNT;
    float* membuf = gmaxA + GCOUNT;

    copy_kernel<<<2048, 256, 0, stream>>>((const float4*)hs, (float4*)out, SDIM * DDIM / 4);
    gq_kernel<<<QDIM, 256, 0, stream>>>(hs, gnn_idx, Wq, bq, gqbuf);
    relprob_kernel<<<QDIM, 256, 0, stream>>>(hs, rel_idx, Wc, bc, relprob);
    phase1_kernel<<<GCOUNT, 256, 0, stream>>>(nodes, Wn, bn, gqbuf, relprob, prob_idx,
                                              gvec, gdenA, gmaxA);
    combine_kernel<<<QDIM * KDIM, 256, 0, stream>>>(gvec, gdenA, gmaxA, membuf);
    out_kernel<<<QDIM, 256, 0, stream>>>(membuf, Wg, bg, gnn_idx, out);
}

// Round 2
// 449.093 us; speedup vs baseline: 3.7540x; 3.7540x over previous
//
#include <hip/hip_runtime.h>
#include <hip/hip_bf16.h>
#include <math.h>

#define QDIM 64
#define KDIM 2
#define NDIM 32
#define MDIM 64
#define EDIM 256
#define DDIM 1024
#define RDIM 200
#define SDIM 8192
#define GCOUNT (QDIM * KDIM * NDIM)  // 4096 groups

typedef short short8_t __attribute__((ext_vector_type(8)));
typedef float f32x4 __attribute__((ext_vector_type(4)));

__device__ __forceinline__ float fast_tanh(float x) {
    x = fminf(fmaxf(x, -15.0f), 15.0f);
    float e = __expf(2.0f * x);
    return (e - 1.0f) / (e + 1.0f);
}

__device__ __forceinline__ uint32_t f2bf(float f) {  // fp32 -> bf16 bits (RNE)
    uint32_t u = __float_as_uint(f);
    return (u + 0x7fffu + ((u >> 16) & 1u)) >> 16;
}
__device__ __forceinline__ float bf2f(uint16_t h) {
    return __uint_as_float(((uint32_t)h) << 16);
}

// K0: copy hidden_states -> out
__global__ __launch_bounds__(256) void copy_kernel(const float4* __restrict__ src,
                                                   float4* __restrict__ dst, int n4) {
    int i = blockIdx.x * 256 + threadIdx.x;
    int stride = gridDim.x * 256;
    for (; i < n4; i += stride) dst[i] = src[i];
}

// Pack Wn [256,1024] fp32 -> bf16 MFMA B-fragment order.
// wnpk[((ntg*8 + ks)*64 + lane)*8 + j] = bf16(Wn[ks*32 + (lane>>4)*8 + j][ntg*16 + (lane&15)])
__global__ __launch_bounds__(256) void pack_wn(const float* __restrict__ Wn,
                                               short* __restrict__ wnpk) {
    int tid = blockIdx.x * 256 + threadIdx.x;  // 0..32767
    int lane = tid & 63, ks = (tid >> 6) & 7, ntg = tid >> 9;
    int low = lane & 15, hi = lane >> 4;
    short8_t o;
#pragma unroll
    for (int j = 0; j < 8; ++j) {
        int k = ks * 32 + hi * 8 + j;
        int d = ntg * 16 + low;
        o[j] = (short)f2bf(Wn[(size_t)k * DDIM + d]);
    }
    *(short8_t*)(wnpk + (size_t)tid * 8) = o;
}

// K1: gq[q][d] = tanh(hs[gnn_idx[q]] @ Wq + bq); 4 blocks per q (256 d-cols each)
__global__ __launch_bounds__(256) void gq_kernel(const float* __restrict__ hs,
                                                 const int* __restrict__ gnn_idx,
                                                 const float* __restrict__ Wq,
                                                 const float* __restrict__ bq,
                                                 float* __restrict__ gqo) {
    int q = blockIdx.x >> 2, seg = blockIdx.x & 3, t = threadIdx.x;
    __shared__ float row[DDIM];
    const float* src = hs + (size_t)gnn_idx[q] * DDIM;
    for (int i = t; i < DDIM; i += 256) row[i] = src[i];
    __syncthreads();
    int d = seg * 256 + t;
    float a = bq[d];
#pragma unroll 4
    for (int k = 0; k < DDIM; ++k) a += row[k] * Wq[(size_t)k * DDIM + d];
    gqo[(size_t)q * DDIM + d] = fast_tanh(a);
}

// K2: rel_prob[q][r] = softmax_r(hs[rel_idx[q]] @ Wc + bc)
__global__ __launch_bounds__(256) void relprob_kernel(const float* __restrict__ hs,
                                                      const int* __restrict__ rel_idx,
                                                      const float* __restrict__ Wc,
                                                      const float* __restrict__ bc,
                                                      float* __restrict__ rel_prob) {
    int q = blockIdx.x, t = threadIdx.x;
    __shared__ float row[DDIM];
    __shared__ float arr[256];
    const float* src = hs + (size_t)rel_idx[q] * DDIM;
    for (int i = t; i < DDIM; i += 256) row[i] = src[i];
    __syncthreads();
    float lg = -INFINITY;
    if (t < RDIM) {
        float a = bc[t];
        for (int k = 0; k < DDIM; ++k) a += row[k] * Wc[(size_t)k * RDIM + t];
        lg = a;
    }
    arr[t] = lg;
    __syncthreads();
    for (int s = 128; s > 0; s >>= 1) {
        if (t < s) arr[t] = fmaxf(arr[t], arr[t + s]);
        __syncthreads();
    }
    float mx = arr[0];
    __syncthreads();
    float ex = (t < RDIM) ? __expf(lg - mx) : 0.0f;
    arr[t] = ex;
    __syncthreads();
    for (int s = 128; s > 0; s >>= 1) {
        if (t < s) arr[t] += arr[t + s];
        __syncthreads();
    }
    float sm = arr[0];
    if (t < RDIM) rel_prob[q * RDIM + t] = ex / sm;
}

// K3: per-(q,k,n) group via bf16 MFMA.
// Stage nodes tile bf16 (XOR-swizzled LDS), hoist A-frags to regs, stream
// packed Wn from L2, epilogue tanh*gq accumulate -> dots; then softmax chain
// and exp-weighted column sum (same math as the verified fp32 version).
__global__ __launch_bounds__(256, 2) void phase1_mfma(
    const float* __restrict__ nodes, const short* __restrict__ wnpk,
    const float* __restrict__ bn, const float* __restrict__ gq,
    const float* __restrict__ rel_prob, const int* __restrict__ prob_idx,
    float* __restrict__ gvec, float* __restrict__ gden, float* __restrict__ gmx) {
    const int g = blockIdx.x;
    const int q = g / (KDIM * NDIM);
    const int t = threadIdx.x;
    const int lane = t & 63, w = t >> 6;
    const int low = lane & 15, hi = lane >> 4;

    __shared__ alignas(16) char ldsbuf[MDIM * EDIM * 2];  // 32KB bf16 tile
    __shared__ float part[4][MDIM];
    __shared__ float lv[MDIM];

    // stage: fp32 global (coalesced float4) -> bf16 swizzled LDS
    {
        const float4* src = (const float4*)(nodes + (size_t)g * (MDIM * EDIM));
#pragma unroll
        for (int i = 0; i < 16; ++i) {
            int idx4 = i * 256 + t;
            float4 v = src[idx4];
            int m = idx4 >> 6;
            int byteoff = (m * 512 + (idx4 & 63) * 8) ^ ((m & 7) << 4);
            uint32_t w0 = f2bf(v.x) | (f2bf(v.y) << 16);
            uint32_t w1 = f2bf(v.z) | (f2bf(v.w) << 16);
            *(uint2*)(ldsbuf + byteoff) = make_uint2(w0, w1);
        }
    }
    __syncthreads();

    // hoist all A fragments (full 64x256 tile in-wave: 128 VGPRs)
    short8_t af[4][8];
#pragma unroll
    for (int mt = 0; mt < 4; ++mt)
#pragma unroll
        for (int ks = 0; ks < 8; ++ks) {
            int row = mt * 16 + low;
            int byteoff = (row * 512 + ks * 64 + hi * 16) ^ ((low & 7) << 4);
            af[mt][ks] = *(const short8_t*)(ldsbuf + byteoff);
        }

    float dacc[4][4] = {};
    const float* gqrow = gq + (size_t)q * DDIM;
    for (int nt = 0; nt < 16; ++nt) {
        const int ntg = w * 16 + nt;
        const int d = ntg * 16 + low;
        float gqv = gqrow[d];
        float bnv = bn[d];
        f32x4 acc0 = {0.f, 0.f, 0.f, 0.f}, acc1 = acc0, acc2 = acc0, acc3 = acc0;
        const short8_t* bp = (const short8_t*)(wnpk) + ((size_t)ntg * 8 * 64 + lane);
#pragma unroll
        for (int ks = 0; ks < 8; ++ks) {
            short8_t bf = bp[ks * 64];
            acc0 = __builtin_amdgcn_mfma_f32_16x16x32_bf16(af[0][ks], bf, acc0, 0, 0, 0);
            acc1 = __builtin_amdgcn_mfma_f32_16x16x32_bf16(af[1][ks], bf, acc1, 0, 0, 0);
            acc2 = __builtin_amdgcn_mfma_f32_16x16x32_bf16(af[2][ks], bf, acc2, 0, 0, 0);
            acc3 = __builtin_amdgcn_mfma_f32_16x16x32_bf16(af[3][ks], bf, acc3, 0, 0, 0);
        }
#pragma unroll
        for (int jj = 0; jj < 4; ++jj) {
            dacc[0][jj] += fast_tanh(acc0[jj] + bnv) * gqv;
            dacc[1][jj] += fast_tanh(acc1[jj] + bnv) * gqv;
            dacc[2][jj] += fast_tanh(acc2[jj] + bnv) * gqv;
            dacc[3][jj] += fast_tanh(acc3[jj] + bnv) * gqv;
        }
    }

    // reduce over the 16 d-columns held by the low lanes; row = mt*16 + hi*4 + jj
#pragma unroll
    for (int mt = 0; mt < 4; ++mt)
#pragma unroll
        for (int jj = 0; jj < 4; ++jj) {
            float v = dacc[mt][jj];
            v += __shfl_xor(v, 1);
            v += __shfl_xor(v, 2);
            v += __shfl_xor(v, 4);
            v += __shfl_xor(v, 8);
            if (low == 0) part[w][mt * 16 + hi * 4 + jj] = v;
        }
    __syncthreads();

    // wave 0: within-group softmax -> logits -> group-local exp weights
    if (t < 64) {
        float dv = part[0][t] + part[1][t] + part[2][t] + part[3][t];
        float mx = dv;
#pragma unroll
        for (int off = 32; off > 0; off >>= 1) mx = fmaxf(mx, __shfl_xor(mx, off));
        float ex = __expf(dv - mx);
        float sm = ex;
#pragma unroll
        for (int off = 32; off > 0; off >>= 1) sm += __shfl_xor(sm, off);
        float attn = ex / sm;
        float pr = rel_prob[(size_t)q * RDIM + prob_idx[g]];
        float lgv = attn * pr * 10.0f;
        float gm = lgv;
#pragma unroll
        for (int off = 32; off > 0; off >>= 1) gm = fmaxf(gm, __shfl_xor(gm, off));
        float el = __expf(lgv - gm);
        float den = el;
#pragma unroll
        for (int off = 32; off > 0; off >>= 1) den += __shfl_xor(den, off);
        unsigned short raw = *(const unsigned short*)(ldsbuf + ((t * 512) ^ ((t & 7) << 4)));
        float msk = ((raw & 0x7fffu) != 0) ? 1.0f : 0.0f;  // mask numerator only
        lv[t] = el * msk;
        if (t == 0) { gden[g] = den; gmx[g] = gm; }
    }
    __syncthreads();

    // vec_n[e] = sum_m nodes_bf16[m][e] * lv[m]; thread t <-> e
    float v = 0.f;
#pragma unroll 8
    for (int m = 0; m < MDIM; ++m) {
        unsigned short raw =
            *(const unsigned short*)(ldsbuf + ((m * 512 + t * 2) ^ ((m & 7) << 4)));
        v += bf2f(raw) * lv[m];
    }
    gvec[(size_t)g * EDIM + t] = v;
}

// K4: per-(q,k) combine 32 groups -> mean_emb[q,k,e]
__global__ __launch_bounds__(256) void combine_kernel(const float* __restrict__ gvec,
                                                      const float* __restrict__ gden,
                                                      const float* __restrict__ gmx,
                                                      float* __restrict__ memb) {
    int qk = blockIdx.x, t = threadIdx.x;
    __shared__ float sgm[NDIM], sden[NDIM];
    if (t < NDIM) {
        sgm[t] = gmx[qk * NDIM + t];
        sden[t] = gden[qk * NDIM + t];
    }
    __syncthreads();
    float gm = -INFINITY;
    for (int n = 0; n < NDIM; ++n) gm = fmaxf(gm, sgm[n]);
    float gs = 0.f;
    for (int n = 0; n < NDIM; ++n) gs += sden[n] * __expf(sgm[n] - gm);
    float me = 0.f;
    for (int n = 0; n < NDIM; ++n)
        me += gvec[(size_t)(qk * NDIM + n) * EDIM + t] * __expf(sgm[n] - gm);
    memb[(size_t)qk * EDIM + t] = me / (gs * (float)(NDIM * MDIM));
}

// K5: pooled = mean_k(mean_emb); out_row = tanh(pooled @ Wg + bg); out[gnn_idx[q]] += row
__global__ __launch_bounds__(256) void out_kernel(const float* __restrict__ memb,
                                                  const float* __restrict__ Wg,
                                                  const float* __restrict__ bg,
                                                  const int* __restrict__ gnn_idx,
                                                  float* __restrict__ out) {
    int q = blockIdx.x, t = threadIdx.x;
    __shared__ float pooled[EDIM];
    pooled[t] = 0.5f * (memb[(size_t)(q * 2 + 0) * EDIM + t] + memb[(size_t)(q * 2 + 1) * EDIM + t]);
    __syncthreads();
    float4 a = ((const float4*)bg)[t];
    const float4* Wg4 = (const float4*)Wg;
    for (int e = 0; e < EDIM; ++e) {
        float p = pooled[e];
        float4 w = Wg4[(size_t)e * (DDIM / 4) + t];
        a.x += p * w.x; a.y += p * w.y; a.z += p * w.z; a.w += p * w.w;
    }
    float4* op = (float4*)(out + (size_t)gnn_idx[q] * DDIM);
    float4 cur = op[t];
    cur.x += fast_tanh(a.x);
    cur.y += fast_tanh(a.y);
    cur.z += fast_tanh(a.z);
    cur.w += fast_tanh(a.w);
    op[t] = cur;
}

extern "C" void kernel_launch(void* const* d_in, const int* in_sizes, int n_in,
                              void* d_out, int out_size, void* d_ws, size_t ws_size,
                              hipStream_t stream) {
    const float* hs = (const float*)d_in[0];
    const float* nodes = (const float*)d_in[1];
    const int* prob_idx = (const int*)d_in[2];
    const int* gnn_idx = (const int*)d_in[3];
    const int* rel_idx = (const int*)d_in[4];
    const float* Wc = (const float*)d_in[5];
    const float* bc = (const float*)d_in[6];
    const float* Wq = (const float*)d_in[7];
    const float* bq = (const float*)d_in[8];
    const float* Wn = (const float*)d_in[9];
    const float* bn = (const float*)d_in[10];
    const float* Wg = (const float*)d_in[11];
    const float* bg = (const float*)d_in[12];
    float* out = (float*)d_out;
    float* ws = (float*)d_ws;

    // ws layout (floats): relprob[16384] | gq[65536] | gvec[4096*256] | gden[4096]
    //                     | gmax[4096] | memb[32768] | wnpk (bf16, 512KB)
    float* relprob = ws;
    float* gqbuf = ws + 16384;
    float* gvec = gqbuf + (size_t)QDIM * DDIM;
    float* gdenA = gvec + (size_t)GCOUNT * EDIM;
    float* gmaxA = gdenA + GCOUNT;
    float* membuf = gmaxA + GCOUNT;
    short* wnpk = (short*)(membuf + (size_t)QDIM * KDIM * EDIM);

    copy_kernel<<<2048, 256, 0, stream>>>((const float4*)hs, (float4*)out, SDIM * DDIM / 4);
    pack_wn<<<128, 256, 0, stream>>>(Wn, wnpk);
    gq_kernel<<<QDIM * 4, 256, 0, stream>>>(hs, gnn_idx, Wq, bq, gqbuf);
    relprob_kernel<<<QDIM, 256, 0, stream>>>(hs, rel_idx, Wc, bc, relprob);
    phase1_mfma<<<GCOUNT, 256, 0, stream>>>(nodes, wnpk, bn, gqbuf, relprob, prob_idx,
                                            gvec, gdenA, gmaxA);
    combine_kernel<<<QDIM * KDIM, 256, 0, stream>>>(gvec, gdenA, gmaxA, membuf);
    out_kernel<<<QDIM, 256, 0, stream>>>(membuf, Wg, bg, gnn_idx, out);
}

// Round 3
// 270.588 us; speedup vs baseline: 6.2305x; 1.6597x over previous
//
#include <hip/hip_runtime.h>
#include <hip/hip_bf16.h>
#include <math.h>

#define QDIM 64
#define KDIM 2
#define NDIM 32
#define MDIM 64
#define EDIM 256
#define DDIM 1024
#define RDIM 200
#define SDIM 8192
#define GCOUNT (QDIM * KDIM * NDIM)  // 4096 groups

typedef short short8_t __attribute__((ext_vector_type(8)));
typedef float f32x4 __attribute__((ext_vector_type(4)));

// tanh(x) = 1 - 2/(1+e^{2x}) : v_mul, v_exp, v_add, v_rcp, v_fma. Saturates
// correctly at +/-inf, no clamp needed. ~1ulp rcp error << bf16 noise.
__device__ __forceinline__ float tanh_c(float x) {
    float e = __expf(2.0f * x);
    return 1.0f - 2.0f * __builtin_amdgcn_rcpf(1.0f + e);
}

__device__ __forceinline__ uint32_t f2bf(float f) {  // fp32 -> bf16 bits (RNE)
    uint32_t u = __float_as_uint(f);
    return (u + 0x7fffu + ((u >> 16) & 1u)) >> 16;
}
__device__ __forceinline__ float bf2f(uint16_t h) {
    return __uint_as_float(((uint32_t)h) << 16);
}

// ---------------- fused prologue ----------------
// blocks [0,2048): copy hs->out          [2048,2176): pack Wn -> bf16 frags
// [2176,2432): gq = tanh(hs[gnn]@Wq)     [2432,2496): rel_prob softmax
// [2496,3520): nv[g] = popcount(nodes[g,:,0] != 0)   (4 groups/block)
__global__ __launch_bounds__(256) void prologue_kernel(
    const float* __restrict__ hs, float* __restrict__ out,
    const float* __restrict__ Wn, short* __restrict__ wnpk,
    const int* __restrict__ gnn_idx, const float* __restrict__ Wq,
    const float* __restrict__ bq, float* __restrict__ gqo,
    const int* __restrict__ rel_idx, const float* __restrict__ Wc,
    const float* __restrict__ bc, float* __restrict__ rel_prob,
    const float* __restrict__ nodes, int* __restrict__ nvarr) {
    const int b = blockIdx.x, t = threadIdx.x;
    __shared__ float row[DDIM];
    __shared__ float arr[256];

    if (b < 2048) {  // ---- copy 32MB
        const float4* src = (const float4*)hs;
        float4* dst = (float4*)out;
        int i = b * 256 + t;
#pragma unroll
        for (int r = 0; r < 4; ++r) dst[i + r * 524288] = src[i + r * 524288];
    } else if (b < 2176) {  // ---- pack Wn
        int tid = (b - 2048) * 256 + t;  // 0..32767
        int lane = tid & 63, ks = (tid >> 6) & 7, ntg = tid >> 9;
        int low = lane & 15, hi = lane >> 4;
        short8_t o;
#pragma unroll
        for (int j = 0; j < 8; ++j) {
            int k = ks * 32 + hi * 8 + j;
            int d = ntg * 16 + low;
            o[j] = (short)f2bf(Wn[(size_t)k * DDIM + d]);
        }
        *(short8_t*)(wnpk + (size_t)tid * 8) = o;
    } else if (b < 2432) {  // ---- gq
        int bb = b - 2176;
        int q = bb >> 2, seg = bb & 3;
        const float* src = hs + (size_t)gnn_idx[q] * DDIM;
        for (int i = t; i < DDIM; i += 256) row[i] = src[i];
        __syncthreads();
        int d = seg * 256 + t;
        float a = bq[d];
#pragma unroll 8
        for (int k = 0; k < DDIM; ++k) a += row[k] * Wq[(size_t)k * DDIM + d];
        gqo[(size_t)q * DDIM + d] = tanh_c(a);
    } else if (b < 2496) {  // ---- rel_prob
        int q = b - 2432;
        const float* src = hs + (size_t)rel_idx[q] * DDIM;
        for (int i = t; i < DDIM; i += 256) row[i] = src[i];
        __syncthreads();
        float lg = -INFINITY;
        if (t < RDIM) {
            float a = bc[t];
            for (int k = 0; k < DDIM; ++k) a += row[k] * Wc[(size_t)k * RDIM + t];
            lg = a;
        }
        arr[t] = lg;
        __syncthreads();
        for (int s = 128; s > 0; s >>= 1) {
            if (t < s) arr[t] = fmaxf(arr[t], arr[t + s]);
            __syncthreads();
        }
        float mx = arr[0];
        __syncthreads();
        float ex = (t < RDIM) ? __expf(lg - mx) : 0.0f;
        arr[t] = ex;
        __syncthreads();
        for (int s = 128; s > 0; s >>= 1) {
            if (t < s) arr[t] += arr[t + s];
            __syncthreads();
        }
        float sm = arr[0];
        if (t < RDIM) rel_prob[q * RDIM + t] = ex / sm;
    } else {  // ---- nv scan: wave per group
        int g = (b - 2496) * 4 + (t >> 6);
        int lane = t & 63;
        float f0 = nodes[(size_t)g * (MDIM * EDIM) + (size_t)lane * EDIM];
        unsigned long long mk = __ballot(f0 != 0.0f);
        if (lane == 0) nvarr[g] = __popcll(mk);
    }
}

// ---------------- phase1 ----------------
struct SharedBufs {
    alignas(16) char ldsbuf[MDIM * EDIM * 2];  // 32KB bf16 swizzled tile
    float part[4][MDIM];
    float cqp[4];
    float lv[MDIM];
};

template <int MT>
__device__ __forceinline__ void phase1_body(
    SharedBufs* sb, int g, int q, const float* __restrict__ nodes,
    const short* __restrict__ wnpk, const float* __restrict__ bn,
    const float* __restrict__ gq, const float* __restrict__ rel_prob,
    const int* __restrict__ prob_idx, float* __restrict__ gvec,
    float* __restrict__ gden, float* __restrict__ gmx) {
    const int t = threadIdx.x;
    const int lane = t & 63, w = t >> 6;
    const int low = lane & 15, hi = lane >> 4;
    constexpr int NS = MT * 16;       // staged slots
    constexpr int TAIL = 64 - NS;     // analytic (all-zero) slots

    // stage MT m-tiles: fp32 global -> bf16 swizzled LDS
    {
        const float4* src = (const float4*)(nodes + (size_t)g * (MDIM * EDIM));
#pragma unroll
        for (int i = 0; i < MT * 4; ++i) {
            int idx4 = i * 256 + t;
            float4 v = src[idx4];
            int m = idx4 >> 6;
            int byteoff = (m * 512 + (idx4 & 63) * 8) ^ ((m & 7) << 4);
            uint32_t w0 = f2bf(v.x) | (f2bf(v.y) << 16);
            uint32_t w1 = f2bf(v.z) | (f2bf(v.w) << 16);
            *(uint2*)(sb->ldsbuf + byteoff) = make_uint2(w0, w1);
        }
    }
    __syncthreads();

    // hoist A fragments for the MT staged tiles
    short8_t af[MT][8];
#pragma unroll
    for (int mt = 0; mt < MT; ++mt)
#pragma unroll
        for (int ks = 0; ks < 8; ++ks) {
            int rrow = mt * 16 + low;
            int byteoff = (rrow * 512 + ks * 64 + hi * 16) ^ ((low & 7) << 4);
            af[mt][ks] = *(const short8_t*)(sb->ldsbuf + byteoff);
        }

    float dacc[MT][4];
#pragma unroll
    for (int mt = 0; mt < MT; ++mt)
#pragma unroll
        for (int jj = 0; jj < 4; ++jj) dacc[mt][jj] = 0.f;

    float cpart = 0.f;  // per-lane partial of c_q = sum_d tanh(bn)*gq
    const float* gqrow = gq + (size_t)q * DDIM;
    for (int nt = 0; nt < 16; ++nt) {
        const int ntg = w * 16 + nt;
        const int d = ntg * 16 + low;
        float gqv = gqrow[d];
        float bnv = bn[d];
        cpart += tanh_c(bnv) * gqv;
        f32x4 acc[MT];
#pragma unroll
        for (int mt = 0; mt < MT; ++mt) acc[mt] = (f32x4){0.f, 0.f, 0.f, 0.f};
        const short8_t* bp = (const short8_t*)(wnpk) + ((size_t)ntg * 8 * 64 + lane);
#pragma unroll
        for (int ks = 0; ks < 8; ++ks) {
            short8_t bf = bp[ks * 64];
#pragma unroll
            for (int mt = 0; mt < MT; ++mt)
                acc[mt] = __builtin_amdgcn_mfma_f32_16x16x32_bf16(af[mt][ks], bf, acc[mt], 0, 0, 0);
        }
#pragma unroll
        for (int mt = 0; mt < MT; ++mt)
#pragma unroll
            for (int jj = 0; jj < 4; ++jj)
                dacc[mt][jj] += tanh_c(acc[mt][jj] + bnv) * gqv;
    }

    // reduce d-partials across 16 low-lanes; slot = mt*16 + hi*4 + jj
#pragma unroll
    for (int mt = 0; mt < MT; ++mt)
#pragma unroll
        for (int jj = 0; jj < 4; ++jj) {
            float v = dacc[mt][jj];
            v += __shfl_xor(v, 1);
            v += __shfl_xor(v, 2);
            v += __shfl_xor(v, 4);
            v += __shfl_xor(v, 8);
            if (low == 0) sb->part[w][mt * 16 + hi * 4 + jj] = v;
        }
    {
        float cw = cpart;
#pragma unroll
        for (int off = 32; off > 0; off >>= 1) cw += __shfl_xor(cw, off);
        if (lane == 0) sb->cqp[w] = cw;
    }
    __syncthreads();

    // wave0: softmax chain with analytic tail (TAIL all-zero slots @ dots=c_q)
    if (t < 64) {
        float cq = 0.25f * (sb->cqp[0] + sb->cqp[1] + sb->cqp[2] + sb->cqp[3]);
        float dv = (t < NS) ? (sb->part[0][t] + sb->part[1][t] + sb->part[2][t] + sb->part[3][t])
                            : -INFINITY;
        float mx = dv;
#pragma unroll
        for (int off = 32; off > 0; off >>= 1) mx = fmaxf(mx, __shfl_xor(mx, off));
        if (TAIL > 0) mx = fmaxf(mx, cq);
        float ex = (t < NS) ? __expf(dv - mx) : 0.0f;
        float sm = ex;
#pragma unroll
        for (int off = 32; off > 0; off >>= 1) sm += __shfl_xor(sm, off);
        float ext = __expf(cq - mx);
        sm += (float)TAIL * ext;
        float pr = rel_prob[(size_t)q * RDIM + prob_idx[g]];
        float attn = ex / sm;
        float lgv = (t < NS) ? attn * pr * 10.0f : -INFINITY;
        float lgvt = (ext / sm) * pr * 10.0f;
        float gm = lgv;
#pragma unroll
        for (int off = 32; off > 0; off >>= 1) gm = fmaxf(gm, __shfl_xor(gm, off));
        if (TAIL > 0) gm = fmaxf(gm, lgvt);
        float el = (t < NS) ? __expf(lgv - gm) : 0.0f;
        float den = el;
#pragma unroll
        for (int off = 32; off > 0; off >>= 1) den += __shfl_xor(den, off);
        den += (float)TAIL * __expf(lgvt - gm);
        if (t < NS) {
            unsigned short raw =
                *(const unsigned short*)(sb->ldsbuf + ((t * 512) ^ ((t & 7) << 4)));
            float msk = ((raw & 0x7fffu) != 0) ? 1.0f : 0.0f;
            sb->lv[t] = el * msk;
        }
        if (t == 0) { gden[g] = den; gmx[g] = gm; }
    }
    __syncthreads();

    // vec[e] = sum over staged m of nodes_bf16[m][e] * lv[m]
    float v = 0.f;
#pragma unroll 8
    for (int m = 0; m < NS; ++m) {
        unsigned short raw =
            *(const unsigned short*)(sb->ldsbuf + ((m * 512 + t * 2) ^ ((m & 7) << 4)));
        v += bf2f(raw) * sb->lv[m];
    }
    gvec[(size_t)g * EDIM + t] = v;
}

__global__ __launch_bounds__(256, 2) void phase1_mfma(
    const float* __restrict__ nodes, const short* __restrict__ wnpk,
    const float* __restrict__ bn, const float* __restrict__ gq,
    const float* __restrict__ rel_prob, const int* __restrict__ prob_idx,
    const int* __restrict__ nvarr, float* __restrict__ gvec,
    float* __restrict__ gden, float* __restrict__ gmx) {
    __shared__ SharedBufs sb;
    const int g = blockIdx.x;
    const int q = g / (KDIM * NDIM);
    int nv = nvarr[g];
    int mtiles = (nv + 15) >> 4;
    if (mtiles < 1) mtiles = 1;
    switch (mtiles) {
        case 1: phase1_body<1>(&sb, g, q, nodes, wnpk, bn, gq, rel_prob, prob_idx, gvec, gden, gmx); break;
        case 2: phase1_body<2>(&sb, g, q, nodes, wnpk, bn, gq, rel_prob, prob_idx, gvec, gden, gmx); break;
        case 3: phase1_body<3>(&sb, g, q, nodes, wnpk, bn, gq, rel_prob, prob_idx, gvec, gden, gmx); break;
        default: phase1_body<4>(&sb, g, q, nodes, wnpk, bn, gq, rel_prob, prob_idx, gvec, gden, gmx); break;
    }
}

// ---------------- combine + out ----------------
__global__ __launch_bounds__(256) void combine_kernel(const float* __restrict__ gvec,
                                                      const float* __restrict__ gden,
                                                      const float* __restrict__ gmx,
                                                      float* __restrict__ memb) {
    int qk = blockIdx.x, t = threadIdx.x;
    __shared__ float sgm[NDIM], sden[NDIM];
    if (t < NDIM) {
        sgm[t] = gmx[qk * NDIM + t];
        sden[t] = gden[qk * NDIM + t];
    }
    __syncthreads();
    float gm = -INFINITY;
    for (int n = 0; n < NDIM; ++n) gm = fmaxf(gm, sgm[n]);
    float gs = 0.f;
    for (int n = 0; n < NDIM; ++n) gs += sden[n] * __expf(sgm[n] - gm);
    float me = 0.f;
    for (int n = 0; n < NDIM; ++n)
        me += gvec[(size_t)(qk * NDIM + n) * EDIM + t] * __expf(sgm[n] - gm);
    memb[(size_t)qk * EDIM + t] = me / (gs * (float)(NDIM * MDIM));
}

__global__ __launch_bounds__(256) void out_kernel(const float* __restrict__ memb,
                                                  const float* __restrict__ Wg,
                                                  const float* __restrict__ bg,
                                                  const int* __restrict__ gnn_idx,
                                                  float* __restrict__ out) {
    int q = blockIdx.x, t = threadIdx.x;
    __shared__ float pooled[EDIM];
    pooled[t] = 0.5f * (memb[(size_t)(q * 2 + 0) * EDIM + t] + memb[(size_t)(q * 2 + 1) * EDIM + t]);
    __syncthreads();
    float4 a = ((const float4*)bg)[t];
    const float4* Wg4 = (const float4*)Wg;
    for (int e = 0; e < EDIM; ++e) {
        float p = pooled[e];
        float4 w = Wg4[(size_t)e * (DDIM / 4) + t];
        a.x += p * w.x; a.y += p * w.y; a.z += p * w.z; a.w += p * w.w;
    }
    float4* op = (float4*)(out + (size_t)gnn_idx[q] * DDIM);
    float4 cur = op[t];
    cur.x += tanh_c(a.x);
    cur.y += tanh_c(a.y);
    cur.z += tanh_c(a.z);
    cur.w += tanh_c(a.w);
    op[t] = cur;
}

extern "C" void kernel_launch(void* const* d_in, const int* in_sizes, int n_in,
                              void* d_out, int out_size, void* d_ws, size_t ws_size,
                              hipStream_t stream) {
    const float* hs = (const float*)d_in[0];
    const float* nodes = (const float*)d_in[1];
    const int* prob_idx = (const int*)d_in[2];
    const int* gnn_idx = (const int*)d_in[3];
    const int* rel_idx = (const int*)d_in[4];
    const float* Wc = (const float*)d_in[5];
    const float* bc = (const float*)d_in[6];
    const float* Wq = (const float*)d_in[7];
    const float* bq = (const float*)d_in[8];
    const float* Wn = (const float*)d_in[9];
    const float* bn = (const float*)d_in[10];
    const float* Wg = (const float*)d_in[11];
    const float* bg = (const float*)d_in[12];
    float* out = (float*)d_out;
    float* ws = (float*)d_ws;

    // ws layout (floats): relprob[16384] | gq[65536] | gvec[1048576] | gden[4096]
    //   | gmax[4096] | memb[32768] | wnpk(bf16: 131072 floats) | nv(int: 4096)
    float* relprob = ws;
    float* gqbuf = ws + 16384;
    float* gvec = gqbuf + (size_t)QDIM * DDIM;
    float* gdenA = gvec + (size_t)GCOUNT * EDIM;
    float* gmaxA = gdenA + GCOUNT;
    float* membuf = gmaxA + GCOUNT;
    short* wnpk = (short*)(membuf + (size_t)QDIM * KDIM * EDIM);
    int* nvarr = (int*)(wnpk + (size_t)EDIM * DDIM);

    prologue_kernel<<<3520, 256, 0, stream>>>(hs, out, Wn, wnpk, gnn_idx, Wq, bq,
                                              gqbuf, rel_idx, Wc, bc, relprob,
                                              nodes, nvarr);
    phase1_mfma<<<GCOUNT, 256, 0, stream>>>(nodes, wnpk, bn, gqbuf, relprob, prob_idx,
                                            nvarr, gvec, gdenA, gmaxA);
    combine_kernel<<<QDIM * KDIM, 256, 0, stream>>>(gvec, gdenA, gmaxA, membuf);
    out_kernel<<<QDIM, 256, 0, stream>>>(membuf, Wg, bg, gnn_idx, out);
}